// Round 11
// baseline (120.696 us; speedup 1.0000x reference)
//
#include <hip/hip_runtime.h>
#include <hip/hip_bf16.h>

// Problem constants
#define CCH   256        // channels C
#define NG    16         // groups
#define GCN   16         // group channels
#define CRD   64         // reduced channels C/R
#define HH    56
#define WWD   56
#define HWP   3136       // 56*56
#define BB    8
#define NPIX  25088      // B*H*W
#define K2    49
#define O2N   784        // K2 * NG
#define EPSV  1e-5f

#define XROWS 62         // 56 + 2*3 padded rows
#define XRW   64         // padded row width (16B-aligned rows; cols 0..61 valid)
#define CHSTR 3968       // 62*64 floats per (b,ch) plane

#define HT    2          // output rows per tile
#define NT    28         // h-tiles (56/2)
#define PIXT  112        // pixels per tile (2*56)
#define WLS   114        // wl per-k stride in f32 words (2*56 + 2 pad)

typedef unsigned short ushort_t;
typedef __attribute__((ext_vector_type(8))) short bf16x8;
typedef __attribute__((ext_vector_type(4))) float f32x4;

// workspace layout (float units)
#define XP_OFF   0                         // fp32 padded x [b][ch][62][64]
#define XP2_SZ   8126464                   // 8*256*3968
#define XT_OFF   8126464                   // x_t bf16 [pix][256]: 6,422,528 shorts
#define YT_OFF   11337728                  // y_t bf16 [pix][64]: 1,605,632 shorts
#define W1B_OFF  12140544                  // W1 bf16 [64][256]
#define W2B_OFF  12148736                  // W2 bf16 padded [800][64]
#define B2P_OFF  12174336                  // b2 padded: 800 floats
#define BNS_OFF  12175136                  // 64
#define BNT_OFF  12175200                  // 64
// end = 12,175,264 floats = 48.7 MB

__device__ __forceinline__ ushort_t f2bf(float f) {
    unsigned u = __builtin_bit_cast(unsigned, f);
    return (ushort_t)((u + 0x7FFFu + ((u >> 16) & 1u)) >> 16);   // RNE
}

// ---------------------------------------------------------------------------
// prep: zero xp HALO only; W1,W2 bf16 (W2 padded to 800 rows); b2 pad; BN fold
// ---------------------------------------------------------------------------
__global__ __launch_bounds__(256) void prep_kernel(const float* __restrict__ W1,
                                                   const float* __restrict__ b1,
                                                   const float* __restrict__ gamma,
                                                   const float* __restrict__ beta,
                                                   const float* __restrict__ mean,
                                                   const float* __restrict__ var,
                                                   const float* __restrict__ W2,
                                                   const float* __restrict__ b2,
                                                   float* __restrict__ ws) {
    int gid = blockIdx.x * 256 + threadIdx.x;
    int stride = gridDim.x * 256;
    uint4 z = {0u, 0u, 0u, 0u};
    uint4* xpv = (uint4*)(ws + XP_OFF);        // plane stride 992 uint4
    for (int e = gid; e < 2048 * 192; e += stride) {
        int plane = e / 192, s = e - plane * 192;
        int row, c4i;
        if (s < 24) {
            int rr = s >> 2;
            row = rr < 3 ? rr : rr + 56;       // rows 0,1,2,59,60,61 full
            c4i = s & 3;
        } else {
            int s2 = s - 24;                   // rows 3..58, uint4 slots 0,14,15
            int rw = s2 / 3;
            int m  = s2 - rw * 3;
            row = 3 + rw;
            c4i = (m == 0) ? 0 : 13 + m;
        }
        xpv[plane * 992 + row * 16 + c4i] = z;
    }

    ushort_t* w1b = (ushort_t*)(ws + W1B_OFF);
    if (gid < CRD * CCH) w1b[gid] = f2bf(W1[gid]);               // [o][c]
    ushort_t* w2b = (ushort_t*)(ws + W2B_OFF);
    if (gid < 800 * CRD) w2b[gid] = (gid < O2N * CRD) ? f2bf(W2[gid]) : (ushort_t)0;
    if (gid < 800) ws[B2P_OFF + gid] = (gid < O2N) ? b2[gid] : 0.f;
    if (gid < CRD) {
        float s = gamma[gid] * rsqrtf(var[gid] + EPSV);
        ws[BNS_OFF + gid] = s;
        ws[BNT_OFF + gid] = (b1[gid] - mean[gid]) * s + beta[gid];
    }
}

// ---------------------------------------------------------------------------
// pack_x: read x ONCE -> x_t[pix][256] bf16 (LDS transpose) + xp fp32 interior
// ---------------------------------------------------------------------------
__global__ __launch_bounds__(256) void pack_x(const float* __restrict__ x,
                                              float* __restrict__ ws) {
    __shared__ ushort_t st[64 * 270];      // pad 256->270 shorts (odd-word row stride)
    int tid = threadIdx.x;
    int b = blockIdx.y, hw0 = blockIdx.x * 64;
    int lane = tid & 63, c4 = tid >> 6;
    int hw = hw0 + lane;
    int h = hw / WWD, w = hw - h * WWD;
    const float* xb = x + (b * CCH) * HWP + hw;
    float* xpd = ws + XP_OFF + (size_t)(b * CCH) * CHSTR + (h + 3) * XRW + (w + 3);
#pragma unroll 8
    for (int i = 0; i < 64; ++i) {
        int c = i * 4 + c4;
        float v = xb[c * HWP];
        st[lane * 270 + c] = f2bf(v);
        xpd[c * CHSTR] = v;
    }
    __syncthreads();
    const unsigned* stu = (const unsigned*)st;           // row stride 135 words
    unsigned* xtu = (unsigned*)(ws + XT_OFF);            // x_t rows: 128 words
    int rowg = b * HWP + hw0;
#pragma unroll
    for (int k = 0; k < 32; ++k) {
        int idx = k * 256 + tid;
        int row = idx >> 7, c2 = idx & 127;
        xtu[(rowg + row) * 128 + c2] = stu[row * 135 + c2];
    }
}

// ---------------------------------------------------------------------------
// conv1 (MFMA bf16): y_t[pix][64] = relu(bns[o]*(x_t @ W1^T)[o][pix] + bnt[o])
// ---------------------------------------------------------------------------
__global__ __launch_bounds__(256) void conv1_mfma(float* __restrict__ ws) {
    const ushort_t* xt  = (const ushort_t*)(ws + XT_OFF);
    const ushort_t* w1b = (const ushort_t*)(ws + W1B_OFF);
    const float* bns = ws + BNS_OFF;
    const float* bnt = ws + BNT_OFF;
    ushort_t* yt = (ushort_t*)(ws + YT_OFF);

    int tid = threadIdx.x, lane = tid & 63, wv = tid >> 6;
    int lr = lane & 15, lg = lane >> 4;
    int ot = blockIdx.x;                                  // 0..3
    int pixbase = blockIdx.y * 128 + wv * 32;

    const bf16x8* ap = (const bf16x8*)(w1b + (ot * 16 + lr) * CCH + lg * 8);
    bf16x8 a[8];
#pragma unroll
    for (int ks = 0; ks < 8; ++ks) a[ks] = ap[ks * 4];

    f32x4 acc[2] = {{0.f,0.f,0.f,0.f}, {0.f,0.f,0.f,0.f}};
#pragma unroll
    for (int f = 0; f < 2; ++f) {
        const bf16x8* bp = (const bf16x8*)(xt + (pixbase + f * 16 + lr) * CCH + lg * 8);
#pragma unroll
        for (int ks = 0; ks < 8; ++ks)
            acc[f] = __builtin_amdgcn_mfma_f32_16x16x32_bf16(a[ks], bp[ks * 4], acc[f], 0, 0, 0);
    }

    int o0 = ot * 16 + lg * 4;
    float4 s4 = *(const float4*)(bns + o0);
    float4 t4 = *(const float4*)(bnt + o0);
#pragma unroll
    for (int f = 0; f < 2; ++f) {
        int pix = pixbase + f * 16 + lr;
        union { ushort_t u[4]; uint2 v; } pk;
        pk.u[0] = f2bf(fmaxf(acc[f][0] * s4.x + t4.x, 0.f));
        pk.u[1] = f2bf(fmaxf(acc[f][1] * s4.y + t4.y, 0.f));
        pk.u[2] = f2bf(fmaxf(acc[f][2] * s4.z + t4.z, 0.f));
        pk.u[3] = f2bf(fmaxf(acc[f][3] * s4.w + t4.w, 0.f));
        *(uint2*)(yt + pix * CRD + o0) = pk.v;
    }
}

// ---------------------------------------------------------------------------
// invol_fused, 2-ROW tiles: per block (g, h0t of 2 rows, b):
//   B)  MFMA (7 pt-tiles of 16 pix): wgt = W2[g] @ y^T, y direct from global
//   B2) wgt -> LDS f32, wlf[k*114 + r*56 + w]  (22.3 KB -> 7 blocks/CU;
//       reads wb/wb+8 2-way free, c4 broadcast; writes lg-stride 456=8 mod 32)
//   C)  involution xr-major over 8 padded rows: 3 live x row-vectors
//       (aligned dwordx4), per valid (ki,r,dj) ONE ds_read_b128 f32 (no
//       converts); 98 reads, 392 FMAs, 2r x 4t outputs per thread
//   NOTE: no min-waves launch_bounds (R9: forced cap -> spill catastrophe)
// ---------------------------------------------------------------------------
__global__ __launch_bounds__(256) void invol_fused(const float* __restrict__ ws,
                                                   float* __restrict__ out) {
    __shared__ __align__(16) float wlf[K2 * WLS];   // 22344 B

    int g   = blockIdx.x;
    int h0t = blockIdx.y;                  // 0..27
    int b   = blockIdx.z;
    int tid = threadIdx.x, lane = tid & 63, wv = tid >> 6;
    int lr = lane & 15, lg = lane >> 4;
    int pix0 = b * HWP + h0t * PIXT;

    const ushort_t* yt  = (const ushort_t*)(ws + YT_OFF);
    const ushort_t* w2b = (const ushort_t*)(ws + W2B_OFF);
    const bf16x8* ar = (const bf16x8*)(w2b + (g * K2 + wv * 16 + lr) * CRD);
    bf16x8 a0 = ar[lg], a1 = ar[4 + lg];   // kstep 0 / 1

    const float* b2p = ws + B2P_OFF;
    float b2v[4];
#pragma unroll
    for (int j = 0; j < 4; ++j)
        b2v[j] = b2p[g * K2 + wv * 16 + lg * 4 + j];   // padded, safe for k>=49

    // ---- Phase B: 7 pt-tiles (112 pixels), 7 f32x4 acc
    f32x4 acc[7];
#pragma unroll
    for (int q = 0; q < 7; ++q) acc[q] = (f32x4){0.f, 0.f, 0.f, 0.f};
#pragma unroll
    for (int q = 0; q < 7; ++q) {
        const bf16x8* bp = (const bf16x8*)(yt + (size_t)(pix0 + q * 16 + lr) * CRD + lg * 8);
        acc[q] = __builtin_amdgcn_mfma_f32_16x16x32_bf16(a0, bp[0], acc[q], 0, 0, 0);
        acc[q] = __builtin_amdgcn_mfma_f32_16x16x32_bf16(a1, bp[4], acc[q], 0, 0, 0);
    }
    // ---- Phase B2: scatter wgt -> wlf[k*114 + r*56 + w]
#pragma unroll
    for (int q = 0; q < 7; ++q) {
        int pix = q * 16 + lr;
        int r = pix / WWD;
        int w = pix - r * WWD;
#pragma unroll
        for (int j = 0; j < 4; ++j) {
            int k = wv * 16 + lg * 4 + j;
            if (k < K2)
                wlf[k * WLS + r * WWD + w] = acc[q][j] + b2v[j];
        }
    }
    __syncthreads();

    // ---- Phase C: lane = (c4, wb). ch = g*16 + wv*4 + c4; outputs 2r x 4t.
    int c4 = lane >> 4, wb = lane & 15;
    if (wb < 14) {
        int ch = g * GCN + wv * 4 + c4;
        const float* xrb = ws + XP_OFF + (size_t)(b * CCH + ch) * CHSTR
                         + (h0t * HT) * XRW + wb * 4;
        const float* wbp = wlf + wb * 4;   // one base, static offsets

        f32x4 acc2[2] = {{0.f,0.f,0.f,0.f},{0.f,0.f,0.f,0.f}};

#define XVe(e) ((e) < 4 ? xu[(e) & 3] : ((e) < 8 ? xm[(e) & 3] : xq[(e) & 3]))
#pragma unroll
        for (int xr = 0; xr < 8; ++xr) {   // padded rows h0..h0+7
            f32x4 xu, xm, xq;
            __builtin_memcpy(&xu, xrb + xr * XRW, 16);
            __builtin_memcpy(&xm, xrb + xr * XRW + 4, 16);
            __builtin_memcpy(&xq, xrb + xr * XRW + 8, 16);
#pragma unroll
            for (int ki = 0; ki < 7; ++ki) {
                int r = xr - ki;            // compile-time after unroll
                if (r >= 0 && r < HT) {
#pragma unroll
                    for (int dj = 0; dj < 7; ++dj) {
                        int k = ki * 7 + dj;
                        f32x4 wr = *(const f32x4*)(wbp + k * WLS + r * WWD);
                        acc2[r][0] = fmaf(XVe(dj + 0), wr[0], acc2[r][0]);
                        acc2[r][1] = fmaf(XVe(dj + 1), wr[1], acc2[r][1]);
                        acc2[r][2] = fmaf(XVe(dj + 2), wr[2], acc2[r][2]);
                        acc2[r][3] = fmaf(XVe(dj + 3), wr[3], acc2[r][3]);
                    }
                }
            }
        }
#undef XVe

        float* ob = out + (size_t)(b * CCH + ch) * HWP + (h0t * HT) * WWD + wb * 4;
#pragma unroll
        for (int r = 0; r < HT; ++r) {
            float4 v = {acc2[r][0], acc2[r][1], acc2[r][2], acc2[r][3]};
            *(float4*)(ob + r * WWD) = v;
        }
    }
}

// ---------------------------------------------------------------------------
extern "C" void kernel_launch(void* const* d_in, const int* in_sizes, int n_in,
                              void* d_out, int out_size, void* d_ws, size_t ws_size,
                              hipStream_t stream) {
    const float* x     = (const float*)d_in[0];
    const float* W1    = (const float*)d_in[1];
    const float* b1    = (const float*)d_in[2];
    const float* gamma = (const float*)d_in[3];
    const float* beta  = (const float*)d_in[4];
    const float* mean  = (const float*)d_in[5];
    const float* var   = (const float*)d_in[6];
    const float* W2    = (const float*)d_in[7];
    const float* b2    = (const float*)d_in[8];

    float* ws  = (float*)d_ws;
    float* out = (float*)d_out;

    prep_kernel<<<1536, 256, 0, stream>>>(W1, b1, gamma, beta, mean, var, W2, b2, ws);
    pack_x<<<dim3(HWP / 64, BB), 256, 0, stream>>>(x, ws);
    conv1_mfma<<<dim3(4, NPIX / 128), 256, 0, stream>>>(ws);
    invol_fused<<<dim3(NG, NT, BB), 256, 0, stream>>>(ws, out);
}

// Round 12
// 89.995 us; speedup vs baseline: 1.3411x; 1.3411x over previous
//
#include <hip/hip_runtime.h>
#include <hip/hip_bf16.h>

// Problem constants
#define CCH   256        // channels C
#define NG    16         // groups
#define GCN   16         // group channels
#define CRD   64         // reduced channels C/R
#define HH    56
#define WWD   56
#define HWP   3136       // 56*56
#define BB    8
#define NPIX  25088      // B*H*W
#define K2    49
#define O2N   784        // K2 * NG
#define EPSV  1e-5f

#define XROWS 62         // 56 + 2*3 padded rows
#define XRW   64         // padded row width (16B-aligned rows; cols 0..61 valid)
#define CHSTR 3968       // 62*64 floats per (b,ch) plane

#define WLK   244        // wl per-k stride in u16 (488 B, 8B-aligned; lg-write offs {0,8,16,24} banks)
#define WLR   60         // wl per-r stride in u16 (120 B, 8B-aligned)

typedef unsigned short ushort_t;
typedef __attribute__((ext_vector_type(8))) short bf16x8;
typedef __attribute__((ext_vector_type(4))) float f32x4;

// workspace layout (float units)
#define XP_OFF   0                         // fp32 padded x [b][ch][62][64]
#define XP2_SZ   8126464                   // 8*256*3968
#define XT_OFF   8126464                   // x_t bf16 [pix][256]: 6,422,528 shorts
#define YT_OFF   11337728                  // y_t bf16 [pix][64]: 1,605,632 shorts
#define W1B_OFF  12140544                  // W1 bf16 [64][256]
#define W2B_OFF  12148736                  // W2 bf16 padded [800][64]
#define B2P_OFF  12174336                  // b2 padded: 800 floats
#define BNS_OFF  12175136                  // 64
#define BNT_OFF  12175200                  // 64
// end = 12,175,264 floats = 48.7 MB

__device__ __forceinline__ ushort_t f2bf(float f) {
    unsigned u = __builtin_bit_cast(unsigned, f);
    return (ushort_t)((u + 0x7FFFu + ((u >> 16) & 1u)) >> 16);   // RNE
}

// ---------------------------------------------------------------------------
// prep: zero xp HALO only; W1,W2 bf16 (W2 padded to 800 rows); b2 pad; BN fold
// ---------------------------------------------------------------------------
__global__ __launch_bounds__(256) void prep_kernel(const float* __restrict__ W1,
                                                   const float* __restrict__ b1,
                                                   const float* __restrict__ gamma,
                                                   const float* __restrict__ beta,
                                                   const float* __restrict__ mean,
                                                   const float* __restrict__ var,
                                                   const float* __restrict__ W2,
                                                   const float* __restrict__ b2,
                                                   float* __restrict__ ws) {
    int gid = blockIdx.x * 256 + threadIdx.x;
    int stride = gridDim.x * 256;
    uint4 z = {0u, 0u, 0u, 0u};
    uint4* xpv = (uint4*)(ws + XP_OFF);        // plane stride 992 uint4
    for (int e = gid; e < 2048 * 192; e += stride) {
        int plane = e / 192, s = e - plane * 192;
        int row, c4i;
        if (s < 24) {
            int rr = s >> 2;
            row = rr < 3 ? rr : rr + 56;       // rows 0,1,2,59,60,61 full
            c4i = s & 3;
        } else {
            int s2 = s - 24;                   // rows 3..58, uint4 slots 0,14,15
            int rw = s2 / 3;
            int m  = s2 - rw * 3;
            row = 3 + rw;
            c4i = (m == 0) ? 0 : 13 + m;
        }
        xpv[plane * 992 + row * 16 + c4i] = z;
    }

    ushort_t* w1b = (ushort_t*)(ws + W1B_OFF);
    if (gid < CRD * CCH) w1b[gid] = f2bf(W1[gid]);               // [o][c]
    ushort_t* w2b = (ushort_t*)(ws + W2B_OFF);
    if (gid < 800 * CRD) w2b[gid] = (gid < O2N * CRD) ? f2bf(W2[gid]) : (ushort_t)0;
    if (gid < 800) ws[B2P_OFF + gid] = (gid < O2N) ? b2[gid] : 0.f;
    if (gid < CRD) {
        float s = gamma[gid] * rsqrtf(var[gid] + EPSV);
        ws[BNS_OFF + gid] = s;
        ws[BNT_OFF + gid] = (b1[gid] - mean[gid]) * s + beta[gid];
    }
}

// ---------------------------------------------------------------------------
// pack_x: read x ONCE -> x_t[pix][256] bf16 (LDS transpose) + xp fp32 interior
// ---------------------------------------------------------------------------
__global__ __launch_bounds__(256) void pack_x(const float* __restrict__ x,
                                              float* __restrict__ ws) {
    __shared__ ushort_t st[64 * 270];      // pad 256->270 shorts (odd-word row stride)
    int tid = threadIdx.x;
    int b = blockIdx.y, hw0 = blockIdx.x * 64;
    int lane = tid & 63, c4 = tid >> 6;
    int hw = hw0 + lane;
    int h = hw / WWD, w = hw - h * WWD;
    const float* xb = x + (b * CCH) * HWP + hw;
    float* xpd = ws + XP_OFF + (size_t)(b * CCH) * CHSTR + (h + 3) * XRW + (w + 3);
#pragma unroll 8
    for (int i = 0; i < 64; ++i) {
        int c = i * 4 + c4;
        float v = xb[c * HWP];
        st[lane * 270 + c] = f2bf(v);
        xpd[c * CHSTR] = v;
    }
    __syncthreads();
    const unsigned* stu = (const unsigned*)st;           // row stride 135 words
    unsigned* xtu = (unsigned*)(ws + XT_OFF);            // x_t rows: 128 words
    int rowg = b * HWP + hw0;
#pragma unroll
    for (int k = 0; k < 32; ++k) {
        int idx = k * 256 + tid;
        int row = idx >> 7, c2 = idx & 127;
        xtu[(rowg + row) * 128 + c2] = stu[row * 135 + c2];
    }
}

// ---------------------------------------------------------------------------
// conv1 (MFMA bf16): y_t[pix][64] = relu(bns[o]*(x_t @ W1^T)[o][pix] + bnt[o])
// ---------------------------------------------------------------------------
__global__ __launch_bounds__(256) void conv1_mfma(float* __restrict__ ws) {
    const ushort_t* xt  = (const ushort_t*)(ws + XT_OFF);
    const ushort_t* w1b = (const ushort_t*)(ws + W1B_OFF);
    const float* bns = ws + BNS_OFF;
    const float* bnt = ws + BNT_OFF;
    ushort_t* yt = (ushort_t*)(ws + YT_OFF);

    int tid = threadIdx.x, lane = tid & 63, wv = tid >> 6;
    int lr = lane & 15, lg = lane >> 4;
    int ot = blockIdx.x;                                  // 0..3
    int pixbase = blockIdx.y * 128 + wv * 32;

    const bf16x8* ap = (const bf16x8*)(w1b + (ot * 16 + lr) * CCH + lg * 8);
    bf16x8 a[8];
#pragma unroll
    for (int ks = 0; ks < 8; ++ks) a[ks] = ap[ks * 4];

    f32x4 acc[2] = {{0.f,0.f,0.f,0.f}, {0.f,0.f,0.f,0.f}};
#pragma unroll
    for (int f = 0; f < 2; ++f) {
        const bf16x8* bp = (const bf16x8*)(xt + (pixbase + f * 16 + lr) * CCH + lg * 8);
#pragma unroll
        for (int ks = 0; ks < 8; ++ks)
            acc[f] = __builtin_amdgcn_mfma_f32_16x16x32_bf16(a[ks], bp[ks * 4], acc[f], 0, 0, 0);
    }

    int o0 = ot * 16 + lg * 4;
    float4 s4 = *(const float4*)(bns + o0);
    float4 t4 = *(const float4*)(bnt + o0);
#pragma unroll
    for (int f = 0; f < 2; ++f) {
        int pix = pixbase + f * 16 + lr;
        union { ushort_t u[4]; uint2 v; } pk;
        pk.u[0] = f2bf(fmaxf(acc[f][0] * s4.x + t4.x, 0.f));
        pk.u[1] = f2bf(fmaxf(acc[f][1] * s4.y + t4.y, 0.f));
        pk.u[2] = f2bf(fmaxf(acc[f][2] * s4.z + t4.z, 0.f));
        pk.u[3] = f2bf(fmaxf(acc[f][3] * s4.w + t4.w, 0.f));
        *(uint2*)(yt + pix * CRD + o0) = pk.v;
    }
}

// ---------------------------------------------------------------------------
// invol_fused (R7 skeleton + bf16 wl):  per block (g, h0-tile of 4 rows, b):
//   B)  MFMA in TWO 7-pt halves (low VGPR, proven): wgt = W2[g] @ y^T,
//       y direct from global (L2-resident; g-fastest grid shares the slice)
//   B2) wgt -> LDS bf16, wl16[k*244 + r*60 + w]  (23.9 KB -> 6 blocks/CU;
//       write banks lg*8 + lr/2 -> 32 banks x 2 lanes = free)
//   C)  involution xr-major (R7's scratch-free form: named xu/xm/xq vecs,
//       aligned dwordx4): per valid (ki,r,dj) ONE ds_read_b64 = 4 bf16 taps
//       (2 B/FMA, half of R7's LDS bytes), 4 bit-op converts + 4 FMAs
// ---------------------------------------------------------------------------
__global__ __launch_bounds__(256) void invol_fused(const float* __restrict__ ws,
                                                   float* __restrict__ out) {
    __shared__ __align__(16) ushort_t wl16[K2 * WLK];   // 23912 B

    int g   = blockIdx.x;
    int h0t = blockIdx.y;                  // 0..13
    int b   = blockIdx.z;
    int tid = threadIdx.x, lane = tid & 63, wv = tid >> 6;
    int lr = lane & 15, lg = lane >> 4;
    int pix0 = b * HWP + h0t * 224;

    const ushort_t* yt  = (const ushort_t*)(ws + YT_OFF);
    const ushort_t* w2b = (const ushort_t*)(ws + W2B_OFF);
    const bf16x8* ar = (const bf16x8*)(w2b + (g * K2 + wv * 16 + lr) * CRD);
    bf16x8 a0 = ar[lg], a1 = ar[4 + lg];   // kstep 0 / 1

    const float* b2p = ws + B2P_OFF;
    float b2v[4];
#pragma unroll
    for (int j = 0; j < 4; ++j)
        b2v[j] = b2p[g * K2 + wv * 16 + lg * 4 + j];   // padded, safe for k>=49

    // ---- Phase B in two halves of 7 pt each (peak regs: 7 f32x4 acc)
#pragma unroll
    for (int half = 0; half < 2; ++half) {
        f32x4 acc[7];
#pragma unroll
        for (int q = 0; q < 7; ++q) acc[q] = (f32x4){0.f, 0.f, 0.f, 0.f};
#pragma unroll
        for (int q = 0; q < 7; ++q) {
            int pt = half * 7 + q;
            const bf16x8* bp = (const bf16x8*)(yt + (size_t)(pix0 + pt * 16 + lr) * CRD + lg * 8);
            acc[q] = __builtin_amdgcn_mfma_f32_16x16x32_bf16(a0, bp[0], acc[q], 0, 0, 0);
            acc[q] = __builtin_amdgcn_mfma_f32_16x16x32_bf16(a1, bp[4], acc[q], 0, 0, 0);
        }
#pragma unroll
        for (int q = 0; q < 7; ++q) {
            int pix = (half * 7 + q) * 16 + lr;
            int r = pix / WWD;
            int w = pix - r * WWD;
#pragma unroll
            for (int j = 0; j < 4; ++j) {
                int k = wv * 16 + lg * 4 + j;
                if (k < K2)
                    wl16[k * WLK + r * WLR + w] = f2bf(acc[q][j] + b2v[j]);
            }
        }
    }
    __syncthreads();

    // ---- Phase C: lane = (c4, wb). ch = g*16 + wv*4 + c4; outputs 4r x 4t.
    int c4 = lane >> 4, wb = lane & 15;
    if (wb < 14) {
        int ch = g * GCN + wv * 4 + c4;
        const float* xrb = ws + XP_OFF + (size_t)(b * CCH + ch) * CHSTR
                         + (h0t * 4) * XRW + wb * 4;
        const char* wkb = (const char*)wl16 + wb * 8;   // one base, static offsets

        f32x4 acc2[4] = {{0.f,0.f,0.f,0.f},{0.f,0.f,0.f,0.f},
                         {0.f,0.f,0.f,0.f},{0.f,0.f,0.f,0.f}};

#define CV0(u) __builtin_bit_cast(float, (unsigned)((u) << 16))
#define CV1(u) __builtin_bit_cast(float, (unsigned)((u) & 0xffff0000u))
#define XVe(e) ((e) < 4 ? xu[(e) & 3] : ((e) < 8 ? xm[(e) & 3] : xq[(e) & 3]))
#pragma unroll
        for (int xr = 0; xr < 10; ++xr) {
            f32x4 xu, xm, xq;
            __builtin_memcpy(&xu, xrb + xr * XRW, 16);
            __builtin_memcpy(&xm, xrb + xr * XRW + 4, 16);
            __builtin_memcpy(&xq, xrb + xr * XRW + 8, 16);
#pragma unroll
            for (int ki = 0; ki < 7; ++ki) {
                int r = xr - ki;            // compile-time after unroll
                if (r >= 0 && r < 4) {
#pragma unroll
                    for (int dj = 0; dj < 7; ++dj) {
                        int k = ki * 7 + dj;
                        uint2 p;            // 4 bf16 taps t0..t3 for (k, r)
                        __builtin_memcpy(&p, wkb + k * (WLK * 2) + r * (WLR * 2), 8);
                        acc2[r][0] = fmaf(XVe(dj + 0), CV0(p.x), acc2[r][0]);
                        acc2[r][1] = fmaf(XVe(dj + 1), CV1(p.x), acc2[r][1]);
                        acc2[r][2] = fmaf(XVe(dj + 2), CV0(p.y), acc2[r][2]);
                        acc2[r][3] = fmaf(XVe(dj + 3), CV1(p.y), acc2[r][3]);
                    }
                }
            }
        }
#undef XVe
#undef CV0
#undef CV1

        float* ob = out + (size_t)(b * CCH + ch) * HWP + (h0t * 4) * WWD + wb * 4;
#pragma unroll
        for (int r = 0; r < 4; ++r) {
            float4 v = {acc2[r][0], acc2[r][1], acc2[r][2], acc2[r][3]};
            *(float4*)(ob + r * WWD) = v;
        }
    }
}

// ---------------------------------------------------------------------------
extern "C" void kernel_launch(void* const* d_in, const int* in_sizes, int n_in,
                              void* d_out, int out_size, void* d_ws, size_t ws_size,
                              hipStream_t stream) {
    const float* x     = (const float*)d_in[0];
    const float* W1    = (const float*)d_in[1];
    const float* b1    = (const float*)d_in[2];
    const float* gamma = (const float*)d_in[3];
    const float* beta  = (const float*)d_in[4];
    const float* mean  = (const float*)d_in[5];
    const float* var   = (const float*)d_in[6];
    const float* W2    = (const float*)d_in[7];
    const float* b2    = (const float*)d_in[8];

    float* ws  = (float*)d_ws;
    float* out = (float*)d_out;

    prep_kernel<<<1536, 256, 0, stream>>>(W1, b1, gamma, beta, mean, var, W2, b2, ws);
    pack_x<<<dim3(HWP / 64, BB), 256, 0, stream>>>(x, ws);
    conv1_mfma<<<dim3(4, NPIX / 128), 256, 0, stream>>>(ws);
    invol_fused<<<dim3(NG, 14, BB), 256, 0, stream>>>(ws, out);
}